// Round 5
// baseline (173.785 us; speedup 1.0000x reference)
//
#include <hip/hip_runtime.h>
#include <math.h>

#define HH 256
#define NN 64
#define LL 4096
#define BB 8
#define CC 8            // L-chunks for parallelism
#define LC (LL / CC)    // 512
#define GG 16           // blocked-Horner group size
#define HN (HH * NN)    // 16384

typedef __attribute__((ext_vector_type(4))) float f4;
typedef const __attribute__((address_space(4))) f4* cf4p;  // constant-space -> s_load

// ws layout (floats):
//   u_ws (float [B][H][L])     @ 327680    (8388608)
//   p_ws (float2[B][H][CC][N]) @ 8716288   (2097152)
//   g    (float [B][H])        @ 10813440  (2048)

// Materialize u[b][h][s] = emb[ids[b][s]][h], coalesced both ways.
// grid = B * 64 s-tiles * 4 h-quarters = 2048 blocks, block = 256.
__global__ __launch_bounds__(256) void gather_kernel(
    const int* __restrict__ ids, const float* __restrict__ emb,
    float* __restrict__ u_ws) {
    int b = blockIdx.x >> 8;
    int rem = blockIdx.x & 255;
    int tile = rem >> 2;   // s-tile 0..63
    int hq = rem & 3;      // h-quarter 0..3
    int t = threadIdx.x;
    int r0 = t >> 6;       // 0..3
    int col = t & 63;
    __shared__ int ids_s[64];
    __shared__ float tb[64][65];   // [s][h'] padded
    if (t < 64) ids_s[t] = ids[b * LL + tile * 64 + t];
    __syncthreads();
    #pragma unroll 4
    for (int rr = 0; rr < 64; rr += 4) {
        int r = rr + r0;
        tb[r][col] = emb[ids_s[r] * HH + hq * 64 + col];  // 256B/wave, coalesced
    }
    __syncthreads();
    #pragma unroll 4
    for (int hh = 0; hh < 64; hh += 4) {
        int h = hh + r0;
        u_ws[(b * HH + hq * 64 + h) * LL + tile * 64 + col] = tb[col][h];
    }
}

// Chunked blocked-Horner scan, SMEM u-loads, constants recomputed in-kernel,
// partial pre-scaled by dA^(512*(CC-1-c)). Fully-unrolled body so the
// scheduler can hoist s_loads several groups ahead (SW pipelining).
// grid = B*H*2 (4096 blocks), block = 256 (4 waves). Wave w -> chunk c.
__global__ __launch_bounds__(256) void scan_kernel(
    const float* __restrict__ u_ws,
    const float* __restrict__ log_dt, const float* __restrict__ A_log_re,
    const float* __restrict__ A_im,
    float2* __restrict__ p_ws) {
    int t = threadIdx.x;
    int w = __builtin_amdgcn_readfirstlane(t >> 6);   // uniform wave id
    int n = t & 63;
    int bh = blockIdx.x >> 1;
    int c = (blockIdx.x & 1) * 4 + w;
    int h = bh & (HH - 1);
    int idx = h * NN + n;

    // dA = exp(dt*A), recomputed per lane (~40 VALU)
    float dt = expf(log_dt[h]);
    float Are = -expf(A_log_re[idx]);
    float Aim = A_im[idx];
    float ea = expf(dt * Are);
    float sn, cs;
    sincosf(dt * Aim, &sn, &cs);
    float dAr = ea * cs, dAi = ea * sn;

    // Qr/Qi[k] = dA^(GG-1-k); R = dA^GG
    float Qr[GG], Qi[GG];
    float qr = 1.0f, qi = 0.0f;
    #pragma unroll
    for (int k = 0; k < GG; ++k) {
        Qr[GG - 1 - k] = qr; Qi[GG - 1 - k] = qi;
        float nr = qr * dAr - qi * dAi;
        float ni = qr * dAi + qi * dAr;
        qr = nr; qi = ni;
    }
    float Rr = qr, Ri = qi;   // dA^16

    cf4p src = (cf4p)(unsigned long long)(u_ws + bh * LL + c * LC);
    float Pr = 0.0f, Pi = 0.0f;
    #pragma unroll
    for (int j = 0; j < LC / GG; ++j) {  // 32 groups of 16, straight-line
        f4 u0 = src[j * 4 + 0];   // s_load: SGPR, no lane replication
        f4 u1 = src[j * 4 + 1];
        f4 u2 = src[j * 4 + 2];
        f4 u3 = src[j * 4 + 3];
        float Tr = 0.0f, Ti = 0.0f;
        Tr = fmaf(u0.x, Qr[0],  Tr); Ti = fmaf(u0.x, Qi[0],  Ti);
        Tr = fmaf(u0.y, Qr[1],  Tr); Ti = fmaf(u0.y, Qi[1],  Ti);
        Tr = fmaf(u0.z, Qr[2],  Tr); Ti = fmaf(u0.z, Qi[2],  Ti);
        Tr = fmaf(u0.w, Qr[3],  Tr); Ti = fmaf(u0.w, Qi[3],  Ti);
        Tr = fmaf(u1.x, Qr[4],  Tr); Ti = fmaf(u1.x, Qi[4],  Ti);
        Tr = fmaf(u1.y, Qr[5],  Tr); Ti = fmaf(u1.y, Qi[5],  Ti);
        Tr = fmaf(u1.z, Qr[6],  Tr); Ti = fmaf(u1.z, Qi[6],  Ti);
        Tr = fmaf(u1.w, Qr[7],  Tr); Ti = fmaf(u1.w, Qi[7],  Ti);
        Tr = fmaf(u2.x, Qr[8],  Tr); Ti = fmaf(u2.x, Qi[8],  Ti);
        Tr = fmaf(u2.y, Qr[9],  Tr); Ti = fmaf(u2.y, Qi[9],  Ti);
        Tr = fmaf(u2.z, Qr[10], Tr); Ti = fmaf(u2.z, Qi[10], Ti);
        Tr = fmaf(u2.w, Qr[11], Tr); Ti = fmaf(u2.w, Qi[11], Ti);
        Tr = fmaf(u3.x, Qr[12], Tr); Ti = fmaf(u3.x, Qi[12], Ti);
        Tr = fmaf(u3.y, Qr[13], Tr); Ti = fmaf(u3.y, Qi[13], Ti);
        Tr = fmaf(u3.z, Qr[14], Tr); Ti = fmaf(u3.z, Qi[14], Ti);
        Tr = fmaf(u3.w, Qr[15], Tr); Ti = fmaf(u3.w, Qi[15], Ti);
        float nr = fmaf(Pr, Rr, fmaf(Pi, -Ri, Tr));
        float ni = fmaf(Pr, Ri, fmaf(Pi, Rr, Ti));
        Pr = nr; Pi = ni;
    }

    // pre-scale by dA^(512*(CC-1-c)):  d512 = (dA^16)^32 via 5 squarings
    float sr = Rr, si = Ri;
    #pragma unroll
    for (int k = 0; k < 5; ++k) {
        float nr = sr * sr - si * si;
        float ni = 2.0f * sr * si;
        sr = nr; si = ni;
    }
    float fr = 1.0f, fi = 0.0f;
    int e = (CC - 1) - c;          // 0..7, wave-uniform
    for (int k = 0; k < e; ++k) {
        float nr = fr * sr - fi * si;
        float ni = fr * si + fi * sr;
        fr = nr; fi = ni;
    }
    float outr = Pr * fr - Pi * fi;
    float outi = Pr * fi + Pi * fr;
    p_ws[(bh * CC + c) * NN + n] = make_float2(outr, outi);
}

// Sum pre-scaled chunk partials, project through w=2*C0*dB, D-term, gelu.
// grid = B*H/4 = 512 blocks, block = 256 (4 waves, one bh each).
__global__ __launch_bounds__(256) void combine_kernel(
    const float2* __restrict__ p_ws,
    const float* __restrict__ log_dt, const float* __restrict__ A_log_re,
    const float* __restrict__ A_im, const float* __restrict__ B_re,
    const float* __restrict__ B_im, const float* __restrict__ C_re,
    const float* __restrict__ C_im,
    const float* __restrict__ u_ws, const float* __restrict__ D,
    float* __restrict__ g) {
    int t = threadIdx.x;
    int bh = blockIdx.x * 4 + (t >> 6);
    int h = bh & (HH - 1);
    int n = t & 63;
    int idx = h * NN + n;

    float Sr = 0.0f, Si = 0.0f;
    #pragma unroll
    for (int c = 0; c < CC; ++c) {
        float2 P = p_ws[(bh * CC + c) * NN + n];
        Sr += P.x; Si += P.y;
    }

    // w = 2*C0*(B*(dA-1)/A), recomputed per lane
    float dt = expf(log_dt[h]);
    float Are = -expf(A_log_re[idx]);
    float Aim = A_im[idx];
    float ea = expf(dt * Are);
    float sn, cs;
    sincosf(dt * Aim, &sn, &cs);
    float dAr = ea * cs, dAi = ea * sn;
    float numre = dAr - 1.0f, numim = dAi;
    float den = Are * Are + Aim * Aim;
    float qre = (numre * Are + numim * Aim) / den;
    float qim = (numim * Are - numre * Aim) / den;
    float bre = B_re[idx], bim = B_im[idx];
    float dBre = bre * qre - bim * qim;
    float dBim = bre * qim + bim * qre;
    float cre = C_re[idx], cim = C_im[idx];
    float wr = 2.0f * (cre * dBre - cim * dBim);
    float wi = 2.0f * (cre * dBim + cim * dBre);

    float contrib = fmaf(wr, Sr, -(wi * Si));
    #pragma unroll
    for (int m = 32; m > 0; m >>= 1) contrib += __shfl_xor(contrib, m);
    if (n == 0) {
        float y = contrib + u_ws[bh * LL + LL - 1] * D[h];
        float ge = 0.5f * y * (1.0f + erff(y * 0.70710678118654752f));
        g[bh] = ge;
    }
}

// Output projection + GLU. grid = B*128 (2 h per block), block = 256 (4 waves).
__global__ __launch_bounds__(256) void out_kernel(
    const float* __restrict__ g, const float* __restrict__ W,
    const float* __restrict__ bvec, float* __restrict__ out) {
    int b = blockIdx.x >> 7;
    int tile = blockIdx.x & 127;
    int t = threadIdx.x;
    int w = t >> 6, lane = t & 63;
    __shared__ float gs[HH];
    __shared__ float zb[4];
    gs[t] = g[b * HH + t];
    __syncthreads();
    int hh = tile * 2 + (w >> 1);
    int o = (w & 1) * HH + hh;
    float4 wv4 = ((const float4*)(W + o * HH))[lane];
    float4 gv4 = ((const float4*)gs)[lane];
    float p = wv4.x * gv4.x + wv4.y * gv4.y + wv4.z * gv4.z + wv4.w * gv4.w;
    #pragma unroll
    for (int m = 32; m > 0; m >>= 1) p += __shfl_xor(p, m);
    if (lane == 0) zb[w] = p + bvec[o];
    __syncthreads();
    if (t < 2) {
        int hq = tile * 2 + t;
        float z1 = zb[t * 2 + 0];
        float z2 = zb[t * 2 + 1];
        out[b * HH + hq] = z1 * (1.0f / (1.0f + expf(-z2)));
    }
}

extern "C" void kernel_launch(void* const* d_in, const int* in_sizes, int n_in,
                              void* d_out, int out_size, void* d_ws, size_t ws_size,
                              hipStream_t stream) {
    const int* input_ids = (const int*)d_in[0];
    const float* embedding = (const float*)d_in[1];
    const float* log_dt = (const float*)d_in[2];
    const float* A_log_re = (const float*)d_in[3];
    const float* A_im = (const float*)d_in[4];
    const float* B_re = (const float*)d_in[5];
    const float* B_im = (const float*)d_in[6];
    const float* C_re = (const float*)d_in[7];
    const float* C_im = (const float*)d_in[8];
    const float* D = (const float*)d_in[9];
    const float* W_out = (const float*)d_in[10];
    const float* b_out = (const float*)d_in[11];
    float* out = (float*)d_out;

    float* ws = (float*)d_ws;
    float* u_ws = ws + 327680;                    // B*H*L floats
    float2* p_ws = (float2*)(ws + 8716288);       // B*H*CC*N float2
    float* g = ws + 10813440;                     // B*H floats

    gather_kernel<<<BB * 64 * 4, 256, 0, stream>>>(input_ids, embedding, u_ws);

    scan_kernel<<<BB * HH * 2, 256, 0, stream>>>(u_ws, log_dt, A_log_re, A_im, p_ws);

    combine_kernel<<<BB * HH / 4, 256, 0, stream>>>(
        p_ws, log_dt, A_log_re, A_im, B_re, B_im, C_re, C_im, u_ws, D, g);

    out_kernel<<<BB * 128, 256, 0, stream>>>(g, W_out, b_out, out);
}

// Round 6
// 137.284 us; speedup vs baseline: 1.2659x; 1.2659x over previous
//
#include <hip/hip_runtime.h>
#include <math.h>

#define HH 256
#define NN 64
#define LL 4096
#define BB 8
#define CC 8            // L-chunks for parallelism
#define LC (LL / CC)    // 512
#define GG 16           // blocked-Horner group size
#define HN (HH * NN)    // 16384

typedef __attribute__((ext_vector_type(4))) float f4;
typedef __attribute__((ext_vector_type(2))) float pf2;
typedef const __attribute__((address_space(4))) f4* cf4p;  // constant-space -> s_load

// ws layout (floats):
//   dA   (float2[HN])          @ 0         (32768 floats)
//   wv   (float2[HN])          @ 32768     (32768)
//   pw   (float2[CC][HN])      @ 65536     (262144)
//   u_ws (float [B][H][L])     @ 327680    (8388608)
//   p_ws (float2[B][H][CC][N]) @ 8716288   (2097152)
//   g    (float [B][H])        @ 10813440  (2048)

__global__ __launch_bounds__(256) void precompute_kernel(
    const float* __restrict__ log_dt, const float* __restrict__ A_log_re,
    const float* __restrict__ A_im, const float* __restrict__ B_re,
    const float* __restrict__ B_im, const float* __restrict__ C_re,
    const float* __restrict__ C_im,
    float2* __restrict__ dAo, float2* __restrict__ wo, float2* __restrict__ pw) {
    int idx = blockIdx.x * blockDim.x + threadIdx.x;  // h*64+n
    if (idx >= HN) return;
    int h = idx / NN;
    float dt = expf(log_dt[h]);
    float Are = -expf(A_log_re[idx]);
    float Aim = A_im[idx];
    float dre = dt * Are, dim = dt * Aim;
    float ea = expf(dre);
    float sn, cs;
    sincosf(dim, &sn, &cs);
    float dAre = ea * cs, dAim = ea * sn;
    // q = (dA - 1)/A ; dB = B*q ; w = 2*C0*dB
    float numre = dAre - 1.0f, numim = dAim;
    float den = Are * Are + Aim * Aim;
    float qre = (numre * Are + numim * Aim) / den;
    float qim = (numim * Are - numre * Aim) / den;
    float bre = B_re[idx], bim = B_im[idx];
    float dBre = bre * qre - bim * qim;
    float dBim = bre * qim + bim * qre;
    float cre = C_re[idx], cim = C_im[idx];
    dAo[idx] = make_float2(dAre, dAim);
    wo[idx] = make_float2(2.0f * (cre * dBre - cim * dBim),
                          2.0f * (cre * dBim + cim * dBre));
    // d512 = dA^512 via 9 squarings
    float pr = dAre, pi = dAim;
    #pragma unroll
    for (int k = 0; k < 9; ++k) {
        float nr = pr * pr - pi * pi;
        float ni = 2.0f * pr * pi;
        pr = nr; pi = ni;
    }
    // pw[k] = dA^(512*k)
    float qr = 1.0f, qi = 0.0f;
    #pragma unroll
    for (int k = 0; k < CC; ++k) {
        pw[k * HN + idx] = make_float2(qr, qi);
        float nr = qr * pr - qi * pi, ni = qr * pi + qi * pr;
        qr = nr; qi = ni;
    }
}

// Materialize u[b][h][s] = emb[ids[b][s]][h], coalesced both ways.
// grid = B * 64 s-tiles * 4 h-quarters = 2048 blocks, block = 256.
__global__ __launch_bounds__(256) void gather_kernel(
    const int* __restrict__ ids, const float* __restrict__ emb,
    float* __restrict__ u_ws) {
    int b = blockIdx.x >> 8;
    int rem = blockIdx.x & 255;
    int tile = rem >> 2;   // s-tile 0..63
    int hq = rem & 3;      // h-quarter 0..3
    int t = threadIdx.x;
    int r0 = t >> 6;       // 0..3
    int col = t & 63;
    __shared__ int ids_s[64];
    __shared__ float tb[64][65];   // [s][h'] padded
    if (t < 64) ids_s[t] = ids[b * LL + tile * 64 + t];
    __syncthreads();
    #pragma unroll 4
    for (int rr = 0; rr < 64; rr += 4) {
        int r = rr + r0;
        tb[r][col] = emb[ids_s[r] * HH + hq * 64 + col];  // 256B/wave, coalesced
    }
    __syncthreads();
    #pragma unroll 4
    for (int hh = 0; hh < 64; hh += 4) {
        int h = hh + r0;
        u_ws[(b * HH + hq * 64 + h) * LL + tile * 64 + col] = tb[col][h];
    }
}

// Chunked blocked-Horner scan: SMEM u-loads (wave-uniform), packed-f32 math.
// (Tr,Ti) += u*(Qr,Qi) is one v_pk_fma_f32; group-Horner = 2 pk_fma.
// grid = B*H*2 (4096 blocks), block = 256 (4 waves). Wave w -> chunk c.
__global__ __launch_bounds__(256) void scan_kernel(
    const float* __restrict__ u_ws, const float2* __restrict__ dAv,
    float2* __restrict__ p_ws) {
    int t = threadIdx.x;
    int w = __builtin_amdgcn_readfirstlane(t >> 6);   // uniform wave id
    int n = t & 63;
    int bh = blockIdx.x >> 1;
    int c = (blockIdx.x & 1) * 4 + w;
    int h = bh & (HH - 1);

    float2 dA = dAv[h * NN + n];
    // Q[k] = dA^(GG-1-k) as (re,im) pairs; R = dA^GG
    pf2 Q[GG];
    pf2 q; q.x = 1.0f; q.y = 0.0f;
    #pragma unroll
    for (int k = 0; k < GG; ++k) {
        Q[GG - 1 - k] = q;
        pf2 nq;
        nq.x = q.x * dA.x - q.y * dA.y;
        nq.y = q.x * dA.y + q.y * dA.x;
        q = nq;
    }
    pf2 Rp; Rp.x = q.x; Rp.y = q.x;      // (Rr, Rr)
    pf2 Rm; Rm.x = -q.y; Rm.y = q.y;     // (-Ri, Ri)

    cf4p src = (cf4p)(unsigned long long)(u_ws + bh * LL + c * LC);
    pf2 P; P.x = 0.0f; P.y = 0.0f;
    #pragma unroll 4
    for (int j = 0; j < LC / GG; ++j) {  // 32 groups of 16
        f4 u0 = src[j * 4 + 0];   // s_load: SGPR, no lane replication
        f4 u1 = src[j * 4 + 1];
        f4 u2 = src[j * 4 + 2];
        f4 u3 = src[j * 4 + 3];
        float us[16] = {u0.x, u0.y, u0.z, u0.w, u1.x, u1.y, u1.z, u1.w,
                        u2.x, u2.y, u2.z, u2.w, u3.x, u3.y, u3.z, u3.w};
        pf2 T; T.x = 0.0f; T.y = 0.0f;
        #pragma unroll
        for (int k = 0; k < GG; ++k) {
            pf2 ub; ub.x = us[k]; ub.y = us[k];
            T = __builtin_elementwise_fma(ub, Q[k], T);   // v_pk_fma_f32
        }
        // P = P*R + T (complex): 2 pk_fma + swap
        pf2 Ps; Ps.x = P.y; Ps.y = P.x;
        P = __builtin_elementwise_fma(P, Rp, __builtin_elementwise_fma(Ps, Rm, T));
    }
    p_ws[(bh * CC + c) * NN + n] = make_float2(P.x, P.y);
}

// Combine chunk partials, project through C, add D-term, gelu.
// grid = B*H/4 = 512 blocks, block = 256 (4 waves, one bh each).
__global__ __launch_bounds__(256) void combine_kernel(
    const float2* __restrict__ p_ws, const float2* __restrict__ pw,
    const float2* __restrict__ wv, const float* __restrict__ u_ws,
    const float* __restrict__ D, float* __restrict__ g) {
    int t = threadIdx.x;
    int bh = blockIdx.x * 4 + (t >> 6);
    int h = bh & (HH - 1);
    int n = t & 63;
    float Sr = 0.0f, Si = 0.0f;
    #pragma unroll
    for (int c = 0; c < CC; ++c) {
        float2 P = p_ws[(bh * CC + c) * NN + n];
        float2 Wp = pw[(CC - 1 - c) * HN + h * NN + n];
        Sr = fmaf(P.x, Wp.x, fmaf(P.y, -Wp.y, Sr));
        Si = fmaf(P.x, Wp.y, fmaf(P.y, Wp.x, Si));
    }
    float2 wc = wv[h * NN + n];
    float contrib = fmaf(wc.x, Sr, -(wc.y * Si));
    #pragma unroll
    for (int m = 32; m > 0; m >>= 1) contrib += __shfl_xor(contrib, m);
    if (n == 0) {
        float y = contrib + u_ws[bh * LL + LL - 1] * D[h];
        float ge = 0.5f * y * (1.0f + erff(y * 0.70710678118654752f));
        g[bh] = ge;
    }
}

// Output projection + GLU. grid = B*128 (2 h per block), block = 256 (4 waves).
__global__ __launch_bounds__(256) void out_kernel(
    const float* __restrict__ g, const float* __restrict__ W,
    const float* __restrict__ bvec, float* __restrict__ out) {
    int b = blockIdx.x >> 7;
    int tile = blockIdx.x & 127;
    int t = threadIdx.x;
    int w = t >> 6, lane = t & 63;
    __shared__ float gs[HH];
    __shared__ float zb[4];
    gs[t] = g[b * HH + t];
    __syncthreads();
    int hh = tile * 2 + (w >> 1);
    int o = (w & 1) * HH + hh;
    float4 wv4 = ((const float4*)(W + o * HH))[lane];
    float4 gv4 = ((const float4*)gs)[lane];
    float p = wv4.x * gv4.x + wv4.y * gv4.y + wv4.z * gv4.z + wv4.w * gv4.w;
    #pragma unroll
    for (int m = 32; m > 0; m >>= 1) p += __shfl_xor(p, m);
    if (lane == 0) zb[w] = p + bvec[o];
    __syncthreads();
    if (t < 2) {
        int hq = tile * 2 + t;
        float z1 = zb[t * 2 + 0];
        float z2 = zb[t * 2 + 1];
        out[b * HH + hq] = z1 * (1.0f / (1.0f + expf(-z2)));
    }
}

extern "C" void kernel_launch(void* const* d_in, const int* in_sizes, int n_in,
                              void* d_out, int out_size, void* d_ws, size_t ws_size,
                              hipStream_t stream) {
    const int* input_ids = (const int*)d_in[0];
    const float* embedding = (const float*)d_in[1];
    const float* log_dt = (const float*)d_in[2];
    const float* A_log_re = (const float*)d_in[3];
    const float* A_im = (const float*)d_in[4];
    const float* B_re = (const float*)d_in[5];
    const float* B_im = (const float*)d_in[6];
    const float* C_re = (const float*)d_in[7];
    const float* C_im = (const float*)d_in[8];
    const float* D = (const float*)d_in[9];
    const float* W_out = (const float*)d_in[10];
    const float* b_out = (const float*)d_in[11];
    float* out = (float*)d_out;

    float* ws = (float*)d_ws;
    float2* dAv = (float2*)ws;                    // HN float2
    float2* wv = (float2*)(ws + 32768);           // HN float2
    float2* pw = (float2*)(ws + 65536);           // CC*HN float2
    float* u_ws = ws + 327680;                    // B*H*L floats
    float2* p_ws = (float2*)(ws + 8716288);       // B*H*CC*N float2
    float* g = ws + 10813440;                     // B*H floats

    precompute_kernel<<<(HN + 255) / 256, 256, 0, stream>>>(
        log_dt, A_log_re, A_im, B_re, B_im, C_re, C_im, dAv, wv, pw);

    gather_kernel<<<BB * 64 * 4, 256, 0, stream>>>(input_ids, embedding, u_ws);

    scan_kernel<<<BB * HH * 2, 256, 0, stream>>>(u_ws, dAv, p_ws);

    combine_kernel<<<BB * HH / 4, 256, 0, stream>>>(p_ws, pw, wv, u_ws, D, g);

    out_kernel<<<BB * 128, 256, 0, stream>>>(g, W_out, b_out, out);
}

// Round 7
// 134.565 us; speedup vs baseline: 1.2915x; 1.0202x over previous
//
#include <hip/hip_runtime.h>
#include <math.h>

#define HH 256
#define NN 64
#define LL 4096
#define BB 8
#define CC 8            // L-chunks for parallelism
#define LC (LL / CC)    // 512
#define GG 16           // blocked-Horner group size
#define HN (HH * NN)    // 16384

typedef __attribute__((ext_vector_type(2))) float pf2;
typedef __attribute__((ext_vector_type(16))) float f16v;
typedef const __attribute__((address_space(4))) f16v* cf16p;  // -> s_load_dwordx16

// ws layout (floats):
//   dA   (float2[HN])          @ 0         (32768 floats)
//   wv   (float2[HN])          @ 32768     (32768)
//   pw   (float2[CC][HN])      @ 65536     (262144)
//   u_ws (float [B][H][L])     @ 327680    (8388608)
//   p_ws (float2[B][H][CC][N]) @ 8716288   (2097152)
//   g    (float [B][H])        @ 10813440  (2048)

__global__ __launch_bounds__(256) void precompute_kernel(
    const float* __restrict__ log_dt, const float* __restrict__ A_log_re,
    const float* __restrict__ A_im, const float* __restrict__ B_re,
    const float* __restrict__ B_im, const float* __restrict__ C_re,
    const float* __restrict__ C_im,
    float2* __restrict__ dAo, float2* __restrict__ wo, float2* __restrict__ pw) {
    int idx = blockIdx.x * blockDim.x + threadIdx.x;  // h*64+n
    if (idx >= HN) return;
    int h = idx / NN;
    float dt = expf(log_dt[h]);
    float Are = -expf(A_log_re[idx]);
    float Aim = A_im[idx];
    float dre = dt * Are, dim = dt * Aim;
    float ea = expf(dre);
    float sn, cs;
    sincosf(dim, &sn, &cs);
    float dAre = ea * cs, dAim = ea * sn;
    // q = (dA - 1)/A ; dB = B*q ; w = 2*C0*dB
    float numre = dAre - 1.0f, numim = dAim;
    float den = Are * Are + Aim * Aim;
    float qre = (numre * Are + numim * Aim) / den;
    float qim = (numim * Are - numre * Aim) / den;
    float bre = B_re[idx], bim = B_im[idx];
    float dBre = bre * qre - bim * qim;
    float dBim = bre * qim + bim * qre;
    float cre = C_re[idx], cim = C_im[idx];
    dAo[idx] = make_float2(dAre, dAim);
    wo[idx] = make_float2(2.0f * (cre * dBre - cim * dBim),
                          2.0f * (cre * dBim + cim * dBre));
    // d512 = dA^512 via 9 squarings
    float pr = dAre, pi = dAim;
    #pragma unroll
    for (int k = 0; k < 9; ++k) {
        float nr = pr * pr - pi * pi;
        float ni = 2.0f * pr * pi;
        pr = nr; pi = ni;
    }
    // pw[k] = dA^(512*k)
    float qr = 1.0f, qi = 0.0f;
    #pragma unroll
    for (int k = 0; k < CC; ++k) {
        pw[k * HN + idx] = make_float2(qr, qi);
        float nr = qr * pr - qi * pi, ni = qr * pi + qi * pr;
        qr = nr; qi = ni;
    }
}

// Materialize u[b][h][s] = emb[ids[b][s]][h]. Each embedding row read ONCE
// (float4, 1 KB coalesced per wave-instr) into a full-width 64x257 LDS tile
// (66 KB -> 2 blocks/CU over 512 blocks), transposed out coalesced.
// grid = B * 64 s-tiles, block = 256.
__global__ __launch_bounds__(256) void gather_kernel(
    const int* __restrict__ ids, const float* __restrict__ emb,
    float* __restrict__ u_ws) {
    int b = blockIdx.x >> 6;
    int tile = blockIdx.x & 63;
    int t = threadIdx.x;
    int w4 = t >> 6, lane = t & 63;
    __shared__ int ids_s[64];
    __shared__ float tb[64][257];   // [s][h], odd stride: transpose reads free
    if (t < 64) ids_s[t] = ids[b * LL + tile * 64 + t];
    __syncthreads();
    // Load: wave w4 handles rows r = w4, w4+4, ... (16 rows, 4 in flight)
    #pragma unroll 4
    for (int r = w4; r < 64; r += 4) {
        float4 v = ((const float4*)(emb + (long)ids_s[r] * HH))[lane];
        tb[r][lane * 4 + 0] = v.x;
        tb[r][lane * 4 + 1] = v.y;
        tb[r][lane * 4 + 2] = v.z;
        tb[r][lane * 4 + 3] = v.w;
    }
    __syncthreads();
    // Store: wave w4 covers h in [w4*64, w4*64+64); 256 B coalesced per instr.
    #pragma unroll 4
    for (int r2 = 0; r2 < 64; ++r2) {
        int h = w4 * 64 + r2;
        u_ws[(b * HH + h) * LL + tile * 64 + lane] = tb[lane][h];
    }
}

// Chunked blocked-Horner scan: s_load_dwordx16 u-loads (one 64B cache line
// per 16-step group), packed-f32 math (v_pk_fma_f32).
// grid = B*H*2 (4096 blocks), block = 256 (4 waves). Wave w -> chunk c.
__global__ __launch_bounds__(256) void scan_kernel(
    const float* __restrict__ u_ws, const float2* __restrict__ dAv,
    float2* __restrict__ p_ws) {
    int t = threadIdx.x;
    int w = __builtin_amdgcn_readfirstlane(t >> 6);   // uniform wave id
    int n = t & 63;
    int bh = blockIdx.x >> 1;
    int c = (blockIdx.x & 1) * 4 + w;
    int h = bh & (HH - 1);

    float2 dA = dAv[h * NN + n];
    // Q[k] = dA^(GG-1-k) as (re,im) pairs; R = dA^GG
    pf2 Q[GG];
    pf2 q; q.x = 1.0f; q.y = 0.0f;
    #pragma unroll
    for (int k = 0; k < GG; ++k) {
        Q[GG - 1 - k] = q;
        pf2 nq;
        nq.x = q.x * dA.x - q.y * dA.y;
        nq.y = q.x * dA.y + q.y * dA.x;
        q = nq;
    }
    pf2 Rp; Rp.x = q.x; Rp.y = q.x;      // (Rr, Rr)
    pf2 Rm; Rm.x = -q.y; Rm.y = q.y;     // (-Ri, Ri)

    cf16p src = (cf16p)(unsigned long long)(u_ws + bh * LL + c * LC);
    pf2 P; P.x = 0.0f; P.y = 0.0f;
    #pragma unroll 4
    for (int j = 0; j < LC / GG; ++j) {  // 32 groups of 16
        f16v u = src[j];                 // one s_load_dwordx16
        pf2 T; T.x = 0.0f; T.y = 0.0f;
        #pragma unroll
        for (int k = 0; k < GG; ++k) {
            pf2 ub; ub.x = u[k]; ub.y = u[k];
            T = __builtin_elementwise_fma(ub, Q[k], T);   // v_pk_fma_f32
        }
        // P = P*R + T (complex): 2 pk_fma + swap
        pf2 Ps; Ps.x = P.y; Ps.y = P.x;
        P = __builtin_elementwise_fma(P, Rp, __builtin_elementwise_fma(Ps, Rm, T));
    }
    p_ws[(bh * CC + c) * NN + n] = make_float2(P.x, P.y);
}

// Combine chunk partials, project through C, add D-term, gelu.
// grid = B*H/4 = 512 blocks, block = 256 (4 waves, one bh each).
__global__ __launch_bounds__(256) void combine_kernel(
    const float2* __restrict__ p_ws, const float2* __restrict__ pw,
    const float2* __restrict__ wv, const float* __restrict__ u_ws,
    const float* __restrict__ D, float* __restrict__ g) {
    int t = threadIdx.x;
    int bh = blockIdx.x * 4 + (t >> 6);
    int h = bh & (HH - 1);
    int n = t & 63;
    float Sr = 0.0f, Si = 0.0f;
    #pragma unroll
    for (int c = 0; c < CC; ++c) {
        float2 P = p_ws[(bh * CC + c) * NN + n];
        float2 Wp = pw[(CC - 1 - c) * HN + h * NN + n];
        Sr = fmaf(P.x, Wp.x, fmaf(P.y, -Wp.y, Sr));
        Si = fmaf(P.x, Wp.y, fmaf(P.y, Wp.x, Si));
    }
    float2 wc = wv[h * NN + n];
    float contrib = fmaf(wc.x, Sr, -(wc.y * Si));
    #pragma unroll
    for (int m = 32; m > 0; m >>= 1) contrib += __shfl_xor(contrib, m);
    if (n == 0) {
        float y = contrib + u_ws[bh * LL + LL - 1] * D[h];
        float ge = 0.5f * y * (1.0f + erff(y * 0.70710678118654752f));
        g[bh] = ge;
    }
}

// Output projection + GLU. grid = B*128 (2 h per block), block = 256 (4 waves).
__global__ __launch_bounds__(256) void out_kernel(
    const float* __restrict__ g, const float* __restrict__ W,
    const float* __restrict__ bvec, float* __restrict__ out) {
    int b = blockIdx.x >> 7;
    int tile = blockIdx.x & 127;
    int t = threadIdx.x;
    int w = t >> 6, lane = t & 63;
    __shared__ float gs[HH];
    __shared__ float zb[4];
    gs[t] = g[b * HH + t];
    __syncthreads();
    int hh = tile * 2 + (w >> 1);
    int o = (w & 1) * HH + hh;
    float4 wv4 = ((const float4*)(W + o * HH))[lane];
    float4 gv4 = ((const float4*)gs)[lane];
    float p = wv4.x * gv4.x + wv4.y * gv4.y + wv4.z * gv4.z + wv4.w * gv4.w;
    #pragma unroll
    for (int m = 32; m > 0; m >>= 1) p += __shfl_xor(p, m);
    if (lane == 0) zb[w] = p + bvec[o];
    __syncthreads();
    if (t < 2) {
        int hq = tile * 2 + t;
        float z1 = zb[t * 2 + 0];
        float z2 = zb[t * 2 + 1];
        out[b * HH + hq] = z1 * (1.0f / (1.0f + expf(-z2)));
    }
}

extern "C" void kernel_launch(void* const* d_in, const int* in_sizes, int n_in,
                              void* d_out, int out_size, void* d_ws, size_t ws_size,
                              hipStream_t stream) {
    const int* input_ids = (const int*)d_in[0];
    const float* embedding = (const float*)d_in[1];
    const float* log_dt = (const float*)d_in[2];
    const float* A_log_re = (const float*)d_in[3];
    const float* A_im = (const float*)d_in[4];
    const float* B_re = (const float*)d_in[5];
    const float* B_im = (const float*)d_in[6];
    const float* C_re = (const float*)d_in[7];
    const float* C_im = (const float*)d_in[8];
    const float* D = (const float*)d_in[9];
    const float* W_out = (const float*)d_in[10];
    const float* b_out = (const float*)d_in[11];
    float* out = (float*)d_out;

    float* ws = (float*)d_ws;
    float2* dAv = (float2*)ws;                    // HN float2
    float2* wv = (float2*)(ws + 32768);           // HN float2
    float2* pw = (float2*)(ws + 65536);           // CC*HN float2
    float* u_ws = ws + 327680;                    // B*H*L floats
    float2* p_ws = (float2*)(ws + 8716288);       // B*H*CC*N float2
    float* g = ws + 10813440;                     // B*H floats

    precompute_kernel<<<(HN + 255) / 256, 256, 0, stream>>>(
        log_dt, A_log_re, A_im, B_re, B_im, C_re, C_im, dAv, wv, pw);

    gather_kernel<<<BB * 64, 256, 0, stream>>>(input_ids, embedding, u_ws);

    scan_kernel<<<BB * HH * 2, 256, 0, stream>>>(u_ws, dAv, p_ws);

    combine_kernel<<<BB * HH / 4, 256, 0, stream>>>(p_ws, pw, wv, u_ws, D, g);

    out_kernel<<<BB * 128, 256, 0, stream>>>(g, W_out, b_out, out);
}

// Round 8
// 131.470 us; speedup vs baseline: 1.3219x; 1.0235x over previous
//
#include <hip/hip_runtime.h>
#include <math.h>

#define HH 256
#define NN 64
#define LL 4096
#define BB 8
#define CC 8            // L-chunks for parallelism (= waves per scan block)
#define LC (LL / CC)    // 512
#define GG 16           // blocked-Horner group size
#define HN (HH * NN)    // 16384

typedef __attribute__((ext_vector_type(2))) float pf2;
typedef __attribute__((ext_vector_type(16))) float f16v;
typedef const __attribute__((address_space(4))) f16v* cf16p;  // -> s_load_dwordx16

// ws layout (floats):
//   dA   (float2[HN])          @ 0         (32768 floats)
//   wv   (float2[HN])          @ 32768     (32768)
//   pw   (float2[CC][HN])      @ 65536     (262144)
//   u_ws (float [B][H][L])     @ 327680    (8388608)
//   g    (float [B][H])        @ 10813440  (2048)

// Fused frontend: blocks [0,512) materialize u (gather+transpose);
// blocks [512,576) do the per-(h,n) constant precompute. Independent work,
// one dispatch, concurrent execution.
__global__ __launch_bounds__(256) void frontend_kernel(
    const int* __restrict__ ids, const float* __restrict__ emb,
    const float* __restrict__ log_dt, const float* __restrict__ A_log_re,
    const float* __restrict__ A_im, const float* __restrict__ B_re,
    const float* __restrict__ B_im, const float* __restrict__ C_re,
    const float* __restrict__ C_im,
    float2* __restrict__ dAo, float2* __restrict__ wo, float2* __restrict__ pw,
    float* __restrict__ u_ws) {
    __shared__ int ids_s[64];
    __shared__ float tb[64][257];   // [s][h], odd stride: transpose reads free
    int t = threadIdx.x;
    if (blockIdx.x < BB * 64) {
        // ---- gather: u[b][h][s] = emb[ids[b][s]][h], coalesced both ways ----
        int b = blockIdx.x >> 6;
        int tile = blockIdx.x & 63;
        int w4 = t >> 6, lane = t & 63;
        if (t < 64) ids_s[t] = ids[b * LL + tile * 64 + t];
        __syncthreads();
        #pragma unroll 4
        for (int r = w4; r < 64; r += 4) {
            float4 v = ((const float4*)(emb + (long)ids_s[r] * HH))[lane];
            tb[r][lane * 4 + 0] = v.x;
            tb[r][lane * 4 + 1] = v.y;
            tb[r][lane * 4 + 2] = v.z;
            tb[r][lane * 4 + 3] = v.w;
        }
        __syncthreads();
        #pragma unroll 4
        for (int r2 = 0; r2 < 64; ++r2) {
            int h = w4 * 64 + r2;
            u_ws[(b * HH + h) * LL + tile * 64 + lane] = tb[lane][h];
        }
    } else {
        // ---- precompute: dA, w = 2*C0*dB, pw[k] = dA^(512k) ----
        int idx = (blockIdx.x - BB * 64) * 256 + t;   // h*64+n
        int h = idx >> 6;
        float dt = expf(log_dt[h]);
        float Are = -expf(A_log_re[idx]);
        float Aim = A_im[idx];
        float ea = expf(dt * Are);
        float sn, cs;
        sincosf(dt * Aim, &sn, &cs);
        float dAre = ea * cs, dAim = ea * sn;
        float numre = dAre - 1.0f, numim = dAim;
        float den = Are * Are + Aim * Aim;
        float qre = (numre * Are + numim * Aim) / den;
        float qim = (numim * Are - numre * Aim) / den;
        float bre = B_re[idx], bim = B_im[idx];
        float dBre = bre * qre - bim * qim;
        float dBim = bre * qim + bim * qre;
        float cre = C_re[idx], cim = C_im[idx];
        dAo[idx] = make_float2(dAre, dAim);
        wo[idx] = make_float2(2.0f * (cre * dBre - cim * dBim),
                              2.0f * (cre * dBim + cim * dBre));
        float pr = dAre, pi = dAim;
        #pragma unroll
        for (int k = 0; k < 9; ++k) {        // dA^512
            float nr = pr * pr - pi * pi;
            float ni = 2.0f * pr * pi;
            pr = nr; pi = ni;
        }
        float qr = 1.0f, qi = 0.0f;
        #pragma unroll
        for (int k = 0; k < CC; ++k) {
            pw[k * HN + idx] = make_float2(qr, qi);
            float nr = qr * pr - qi * pi, ni = qr * pi + qi * pr;
            qr = nr; qi = ni;
        }
    }
}

// Fused scan+combine: one block per (b,h), 8 waves = 8 L-chunks. Each wave:
// blocked-Horner with s_load_dwordx16 u-loads + v_pk_fma_f32, scales its
// partial by pw[7-c] in-register, drops it in LDS; wave 0 reduces, projects
// through wv, adds D-term, GELU, writes g. No p_ws global round-trip.
// grid = B*H = 2048 blocks, block = 512.
__global__ __launch_bounds__(512) void scan_kernel(
    const float* __restrict__ u_ws, const float2* __restrict__ dAv,
    const float2* __restrict__ pw, const float2* __restrict__ wv,
    const float* __restrict__ D, float* __restrict__ g) {
    __shared__ float2 part[CC][NN];   // 4 KB
    int t = threadIdx.x;
    int c = __builtin_amdgcn_readfirstlane(t >> 6);   // wave id = chunk
    int n = t & 63;
    int bh = blockIdx.x;
    int h = bh & (HH - 1);

    float2 dA = dAv[h * NN + n];
    // Q[k] = dA^(GG-1-k) as (re,im) pairs; R = dA^GG
    pf2 Q[GG];
    pf2 q; q.x = 1.0f; q.y = 0.0f;
    #pragma unroll
    for (int k = 0; k < GG; ++k) {
        Q[GG - 1 - k] = q;
        pf2 nq;
        nq.x = q.x * dA.x - q.y * dA.y;
        nq.y = q.x * dA.y + q.y * dA.x;
        q = nq;
    }
    pf2 Rp; Rp.x = q.x; Rp.y = q.x;      // (Rr, Rr)
    pf2 Rm; Rm.x = -q.y; Rm.y = q.y;     // (-Ri, Ri)

    cf16p src = (cf16p)(unsigned long long)(u_ws + bh * LL + c * LC);
    pf2 P; P.x = 0.0f; P.y = 0.0f;
    #pragma unroll 4
    for (int j = 0; j < LC / GG; ++j) {  // 32 groups of 16
        f16v u = src[j];                 // one s_load_dwordx16
        pf2 T; T.x = 0.0f; T.y = 0.0f;
        #pragma unroll
        for (int k = 0; k < GG; ++k) {
            pf2 ub; ub.x = u[k]; ub.y = u[k];
            T = __builtin_elementwise_fma(ub, Q[k], T);   // v_pk_fma_f32
        }
        // P = P*R + T (complex): 2 pk_fma + swap
        pf2 Ps; Ps.x = P.y; Ps.y = P.x;
        P = __builtin_elementwise_fma(P, Rp, __builtin_elementwise_fma(Ps, Rm, T));
    }
    // scale by dA^(512*(CC-1-c)) and stash in LDS
    float2 sc = pw[(CC - 1 - c) * HN + h * NN + n];
    part[c][n] = make_float2(P.x * sc.x - P.y * sc.y,
                             P.x * sc.y + P.y * sc.x);
    __syncthreads();

    if (c == 0) {
        float Sr = 0.0f, Si = 0.0f;
        #pragma unroll
        for (int cc = 0; cc < CC; ++cc) {
            float2 v = part[cc][n];
            Sr += v.x; Si += v.y;
        }
        float2 wc = wv[h * NN + n];
        float contrib = fmaf(wc.x, Sr, -(wc.y * Si));
        #pragma unroll
        for (int m = 32; m > 0; m >>= 1) contrib += __shfl_xor(contrib, m);
        if (n == 0) {
            float y = contrib + u_ws[bh * LL + LL - 1] * D[h];
            float ge = 0.5f * y * (1.0f + erff(y * 0.70710678118654752f));
            g[bh] = ge;
        }
    }
}

// Output projection + GLU. grid = B*128 (2 h per block), block = 256 (4 waves).
__global__ __launch_bounds__(256) void out_kernel(
    const float* __restrict__ g, const float* __restrict__ W,
    const float* __restrict__ bvec, float* __restrict__ out) {
    int b = blockIdx.x >> 7;
    int tile = blockIdx.x & 127;
    int t = threadIdx.x;
    int w = t >> 6, lane = t & 63;
    __shared__ float gs[HH];
    __shared__ float zb[4];
    gs[t] = g[b * HH + t];
    __syncthreads();
    int hh = tile * 2 + (w >> 1);
    int o = (w & 1) * HH + hh;
    float4 wv4 = ((const float4*)(W + o * HH))[lane];
    float4 gv4 = ((const float4*)gs)[lane];
    float p = wv4.x * gv4.x + wv4.y * gv4.y + wv4.z * gv4.z + wv4.w * gv4.w;
    #pragma unroll
    for (int m = 32; m > 0; m >>= 1) p += __shfl_xor(p, m);
    if (lane == 0) zb[w] = p + bvec[o];
    __syncthreads();
    if (t < 2) {
        int hq = tile * 2 + t;
        float z1 = zb[t * 2 + 0];
        float z2 = zb[t * 2 + 1];
        out[b * HH + hq] = z1 * (1.0f / (1.0f + expf(-z2)));
    }
}

extern "C" void kernel_launch(void* const* d_in, const int* in_sizes, int n_in,
                              void* d_out, int out_size, void* d_ws, size_t ws_size,
                              hipStream_t stream) {
    const int* input_ids = (const int*)d_in[0];
    const float* embedding = (const float*)d_in[1];
    const float* log_dt = (const float*)d_in[2];
    const float* A_log_re = (const float*)d_in[3];
    const float* A_im = (const float*)d_in[4];
    const float* B_re = (const float*)d_in[5];
    const float* B_im = (const float*)d_in[6];
    const float* C_re = (const float*)d_in[7];
    const float* C_im = (const float*)d_in[8];
    const float* D = (const float*)d_in[9];
    const float* W_out = (const float*)d_in[10];
    const float* b_out = (const float*)d_in[11];
    float* out = (float*)d_out;

    float* ws = (float*)d_ws;
    float2* dAv = (float2*)ws;                    // HN float2
    float2* wv = (float2*)(ws + 32768);           // HN float2
    float2* pw = (float2*)(ws + 65536);           // CC*HN float2
    float* u_ws = ws + 327680;                    // B*H*L floats
    float* g = ws + 10813440;                     // B*H floats

    frontend_kernel<<<BB * 64 + HN / 256, 256, 0, stream>>>(
        input_ids, embedding, log_dt, A_log_re, A_im, B_re, B_im, C_re, C_im,
        dAv, wv, pw, u_ws);

    scan_kernel<<<BB * HH, 512, 0, stream>>>(u_ws, dAv, pw, wv, D, g);

    out_kernel<<<BB * 128, 256, 0, stream>>>(g, W_out, b_out, out);
}